// Round 8
// baseline (104.596 us; speedup 1.0000x reference)
//
#include <hip/hip_runtime.h>
#include <cstdint>
#include <cstddef>

// Problem constants
#define B_    16
#define S_    1024
#define D_    512
#define P_    256
#define MAXS_ 2048

typedef unsigned short u16;
typedef unsigned int   u32;
typedef _Float16 f16;
typedef _Float16 f16x8 __attribute__((ext_vector_type(8)));
typedef float  f32x4  __attribute__((ext_vector_type(4)));
typedef unsigned short u16x4 __attribute__((ext_vector_type(4)));
typedef unsigned short u16x8 __attribute__((ext_vector_type(8)));

__device__ __forceinline__ void gld_lds16(const void* g, void* l) {
  __builtin_amdgcn_global_load_lds(
      (const __attribute__((address_space(1))) u32*)g,
      (__attribute__((address_space(3))) u32*)l, 16, 0, 0);
}

__device__ __forceinline__ u16 f2h(float f) {
  return __builtin_bit_cast(u16, (f16)f);
}
__device__ __forceinline__ float h2f(u16 h) {
  return (float)__builtin_bit_cast(f16, h);
}

template<int N> __device__ __forceinline__ void waitvm() {
  if constexpr (N == 0)      asm volatile("s_waitcnt vmcnt(0)" ::: "memory");
  else if constexpr (N == 4) asm volatile("s_waitcnt vmcnt(4)" ::: "memory");
  else if constexpr (N == 5) asm volatile("s_waitcnt vmcnt(5)" ::: "memory");
  else static_assert(N == 0, "unsupported vmcnt literal");
}

// ---------------------------------------------------------------------------
// f32 -> f16 convert (data, W)
// ---------------------------------------------------------------------------
__global__ void convert_f16_kernel(const float* __restrict__ src, u16* __restrict__ dst, long n4) {
  long stride = (long)gridDim.x * blockDim.x;
  for (long i = (long)blockIdx.x * blockDim.x + threadIdx.x; i < n4; i += stride) {
    float4 v = ((const float4*)src)[i];
    u16x4 o;
    o[0] = f2h(v.x); o[1] = f2h(v.y); o[2] = f2h(v.z); o[3] = f2h(v.w);
    ((u16x4*)dst)[i] = o;
  }
}

// ---------------------------------------------------------------------------
// QK^T, slot-pipelined (frozen — identical to rounds 5-7 for attribution).
// ---------------------------------------------------------------------------
__global__ __launch_bounds__(512, 2) void qk_pipe(
    const u16* __restrict__ A, u16* __restrict__ Cout, float scale) {
  extern __shared__ __align__(16) char smem[];   // 4 * 32768
  const int tid  = threadIdx.x;
  const int lane = tid & 63;
  const int w    = tid >> 6;
  const int wm   = w >> 2;        // 0..1
  const int wn   = w & 3;         // 0..3
  const int lr   = lane & 15;
  const int hi   = lane >> 4;

  const int bz = blockIdx.z;
  const int I0 = blockIdx.y * 256;
  const int J0 = blockIdx.x * 256;
  const u16* Ab = A + (long)bz * (S_ * D_);

  auto stageP = [&](int s, int part) {
    if (s >= 16) return;
    char* dst = smem + (s & 3) * 32768 + part * 16384;
    const int base = part ? J0 : I0;
    const int k0 = s * 32;
    #pragma unroll
    for (int i = 0; i < 2; ++i) {
      int cid   = i * 512 + tid;
      int inner = cid >> 2;
      int c     = (cid & 3) ^ ((inner >> 1) & 3);
      gld_lds16(Ab + (size_t)(base + inner) * D_ + k0 + c * 8, dst + cid * 16);
    }
  };

  f32x4 acc[8][4] = {};

  stageP(0, 0); stageP(0, 1);
  stageP(1, 0); stageP(1, 1);
  stageP(2, 0); stageP(2, 1);
  asm volatile("s_waitcnt vmcnt(8)" ::: "memory");
  __builtin_amdgcn_s_barrier();

  for (int s = 0; s < 16; ++s) {
    const char* sl = smem + (s & 3) * 32768;
    f16x8 bf[4];
    // ---- phase 0 ----
    {
      f16x8 af[4];
      #pragma unroll
      for (int mq = 0; mq < 4; ++mq) {
        int row = wm * 128 + mq * 16 + lr;
        int cp  = hi ^ ((row >> 1) & 3);
        af[mq] = *(const f16x8*)(sl + row * 64 + cp * 16);
      }
      #pragma unroll
      for (int n = 0; n < 4; ++n) {
        int row = wn * 64 + n * 16 + lr;
        int cp  = hi ^ ((row >> 1) & 3);
        bf[n] = *(const f16x8*)(sl + 16384 + row * 64 + cp * 16);
      }
      stageP(s + 3, 0);
      __builtin_amdgcn_s_barrier();
      asm volatile("s_waitcnt lgkmcnt(0)" ::: "memory");
      __builtin_amdgcn_sched_barrier(0);
      __builtin_amdgcn_s_setprio(1);
      #pragma unroll
      for (int mq = 0; mq < 4; ++mq)
        #pragma unroll
        for (int n = 0; n < 4; ++n)
          acc[mq][n] = __builtin_amdgcn_mfma_f32_16x16x32_f16(af[mq], bf[n], acc[mq][n], 0, 0, 0);
      __builtin_amdgcn_s_setprio(0);
      __builtin_amdgcn_s_barrier();
    }
    // ---- phase 1 ----
    {
      f16x8 af[4];
      #pragma unroll
      for (int mq = 0; mq < 4; ++mq) {
        int row = wm * 128 + 64 + mq * 16 + lr;
        int cp  = hi ^ ((row >> 1) & 3);
        af[mq] = *(const f16x8*)(sl + row * 64 + cp * 16);
      }
      stageP(s + 3, 1);
      __builtin_amdgcn_s_barrier();
      asm volatile("s_waitcnt lgkmcnt(0)" ::: "memory");
      __builtin_amdgcn_sched_barrier(0);
      __builtin_amdgcn_s_setprio(1);
      #pragma unroll
      for (int mq = 0; mq < 4; ++mq)
        #pragma unroll
        for (int n = 0; n < 4; ++n)
          acc[4 + mq][n] = __builtin_amdgcn_mfma_f32_16x16x32_f16(af[mq], bf[n], acc[4 + mq][n], 0, 0, 0);
      __builtin_amdgcn_s_setprio(0);
      if (s <= 12)      asm volatile("s_waitcnt vmcnt(8)" ::: "memory");
      else if (s == 13) asm volatile("s_waitcnt vmcnt(4)" ::: "memory");
      else if (s == 14) asm volatile("s_waitcnt vmcnt(0)" ::: "memory");
      __builtin_amdgcn_s_barrier();
    }
  }

  u16* Cb = Cout + (long)bz * S_ * S_;
  const int row0 = I0 + wm * 128;
  const int col0 = J0 + wn * 64;
  #pragma unroll
  for (int m = 0; m < 8; ++m) {
    #pragma unroll
    for (int i = 0; i < 4; ++i) {
      int r = row0 + m * 16 + (hi << 2) + i;
      #pragma unroll
      for (int n = 0; n < 4; ++n) {
        int c = col0 + n * 16 + lr;
        Cb[(size_t)r * S_ + c] = f2h(acc[m][n][i] * scale);
      }
    }
  }
}

// ---------------------------------------------------------------------------
// Row stats: scores [16384][1024] f16 -> (max, 1/sumexp) float2 per row.
// ---------------------------------------------------------------------------
__global__ __launch_bounds__(256) void stats_kernel(
    const u16* __restrict__ scores, float2* __restrict__ rowstat) {
  const int lane = threadIdx.x & 63;
  const int wv   = threadIdx.x >> 6;
  const long row = (long)blockIdx.x * 4 + wv;
  const u16* src = scores + row * S_;

  u16x8 a0 = *(const u16x8*)&src[lane * 16];
  u16x8 a1 = *(const u16x8*)&src[lane * 16 + 8];
  float v[16];
  #pragma unroll
  for (int j = 0; j < 8; ++j) { v[j] = h2f(a0[j]); v[8 + j] = h2f(a1[j]); }

  float mx = v[0];
  #pragma unroll
  for (int j = 1; j < 16; ++j) mx = fmaxf(mx, v[j]);
  #pragma unroll
  for (int off = 32; off > 0; off >>= 1)
    mx = fmaxf(mx, __shfl_xor(mx, off));

  const float l2e = 1.4426950408889634f;
  float sum = 0.f;
  #pragma unroll
  for (int j = 0; j < 16; ++j) sum += exp2f((v[j] - mx) * l2e);
  #pragma unroll
  for (int off = 32; off > 0; off >>= 1)
    sum += __shfl_xor(sum, off);

  if (lane == 0) rowstat[row] = make_float2(mx, 1.f / sum);
}

// ---------------------------------------------------------------------------
// pv_ring: out[b][:S] = softmax(scores[b]) @ VWT[b]^T + bias, ring-pipelined.
//   Block = 64 q x 256 P, 4 waves 1Mx4N -> wave tile 64x64 (MF4xNF4).
//   K = 1024 kv split into 32 slots of BK=32 (64B rows -> frag reads tile all
//   32 banks: conflict-free without swizzle).
//   B (VWT): gld_lds, 4-buf ring, staged 3 slots ahead.
//   A (scores): reg-load 4 slots ahead (named rA0-3, static rotation),
//     exp2((s-m)*l2e)*il, ds_write 2 slots ahead into 4-buf A-ring.
//   Frag prefetch: slot s reads frags(s+1) before MFMA(s) (ds || MFMA).
//   One counted vmcnt(5) + one barrier per slot; drain only in last slots.
//   grid (1,32,16): yt>=16 blocks zero-fill tail rows 1024..2047.
// ---------------------------------------------------------------------------
__global__ __launch_bounds__(256, 1) void pv_ring(
    const u16* __restrict__ scores, const u16* __restrict__ VWT,
    const float2* __restrict__ rowstat,
    float* __restrict__ out, const float* __restrict__ bias) {
  extern __shared__ __align__(16) char smem[];   // 16K (A ring) + 64K (B ring)
  const int tid  = threadIdx.x;
  const int lane = tid & 63;
  const int wv   = tid >> 6;
  const int lr   = lane & 15;
  const int hi   = lane >> 4;
  const int bz   = blockIdx.z;
  const int yt   = blockIdx.y;

  float* ob = out + (long)bz * MAXS_ * P_;
  if (yt >= 16) {                      // zero tail rows 1024..2047
    float4* o = (float4*)(ob + (size_t)yt * 64 * P_);
    for (int i = tid; i < 64 * P_ / 4; i += 256)
      o[i] = make_float4(0.f, 0.f, 0.f, 0.f);
    return;
  }

  const int q0 = yt * 64;
  const u16* sb = scores + ((long)bz * S_ + q0) * S_;
  const u16* Vb = VWT + (long)bz * P_ * S_;
  const int arow = tid >> 2;           // 0..63: q-row this thread stages
  const int ac   = tid & 3;            // 16B chunk within the 64B slot-row
  const float2 st = rowstat[(long)bz * S_ + q0 + arow];
  const float am = st.x, ail = st.y;
  const float l2e = 1.4426950408889634f;

  auto loadA = [&](int s) -> u16x8 {
    return *(const u16x8*)(sb + (size_t)arow * S_ + s * 32 + ac * 8);
  };
  auto writeA = [&](int s, u16x8 r) {
    u16x8 p;
    #pragma unroll
    for (int j = 0; j < 8; ++j)
      p[j] = f2h(exp2f((h2f(r[j]) - am) * l2e) * ail);
    *(u16x8*)(smem + (s & 3) * 4096 + arow * 64 + ac * 16) = p;
  };
  auto stageB = [&](int s) {           // 16 KB: 256 P-rows x 32 k (64B rows)
    char* dB = smem + 16384 + (s & 3) * 16384;
    const int k0 = s * 32;
    #pragma unroll
    for (int i = 0; i < 4; ++i) {
      int cid = i * 256 + tid;
      gld_lds16(Vb + (size_t)(cid >> 2) * S_ + k0 + (cid & 3) * 8, dB + cid * 16);
    }
  };
  auto fragRead = [&](int s, f16x8 (&af)[4], f16x8 (&bf)[4]) {
    const char* aB = smem + (s & 3) * 4096;
    const char* bB = smem + 16384 + (s & 3) * 16384;
    #pragma unroll
    for (int m = 0; m < 4; ++m)
      af[m] = *(const f16x8*)(aB + (m * 16 + lr) * 64 + hi * 16);
    #pragma unroll
    for (int n = 0; n < 4; ++n)
      bf[n] = *(const f16x8*)(bB + (wv * 64 + n * 16 + lr) * 64 + hi * 16);
  };

  f32x4 acc[4][4] = {};
  auto mfma16 = [&](f16x8 (&af)[4], f16x8 (&bf)[4]) {
    __builtin_amdgcn_s_setprio(1);
    #pragma unroll
    for (int m = 0; m < 4; ++m)
      #pragma unroll
      for (int n = 0; n < 4; ++n)
        acc[m][n] = __builtin_amdgcn_mfma_f32_16x16x32_f16(af[m], bf[n], acc[m][n], 0, 0, 0);
    __builtin_amdgcn_s_setprio(0);
  };

  f16x8 aF0[4], bF0[4], aF1[4], bF1[4];
  u16x8 rA0, rA1, rA2, rA3;

  // ---- prologue: A(0..3) to regs, B(0..2) staged ----
  rA0 = loadA(0); rA1 = loadA(1); rA2 = loadA(2); rA3 = loadA(3);
  __builtin_amdgcn_sched_barrier(0);
  stageB(0); stageB(1); stageB(2);
  __builtin_amdgcn_sched_barrier(0);
  waitvm<4>();                         // A0-3, B0, B1 landed (B2 in flight)
  writeA(0, rA0); writeA(1, rA1);
  asm volatile("s_waitcnt lgkmcnt(0)" ::: "memory");
  __builtin_amdgcn_s_barrier();
  fragRead(0, aF0, bF0);
  asm volatile("s_waitcnt lgkmcnt(0)" ::: "memory");
  __builtin_amdgcn_sched_barrier(0);

  // slot s: load A(s+4)->dstA, stage B(s+3), prefetch frags(s+1),
  //         MFMA(s), vmcnt(5), writeA(s+2)<-srcA, barrier.
  auto slot = [&](int s, u16x8& dstA, u16x8 srcA,
                  f16x8 (&afc)[4], f16x8 (&bfc)[4],
                  f16x8 (&afn)[4], f16x8 (&bfn)[4]) {
    dstA = loadA(s + 4);
    __builtin_amdgcn_sched_barrier(0);
    stageB(s + 3);
    __builtin_amdgcn_sched_barrier(0);
    fragRead(s + 1, afn, bfn);
    mfma16(afc, bfc);
    waitvm<5>();                       // retires A(s+2), B(s+2) and older
    writeA(s + 2, srcA);
    asm volatile("s_waitcnt lgkmcnt(0)" ::: "memory");
    __builtin_amdgcn_s_barrier();
    __builtin_amdgcn_sched_barrier(0);
  };

  for (int s0 = 0; s0 < 28; s0 += 4) {
    slot(s0 + 0, rA0, rA2, aF0, bF0, aF1, bF1);
    slot(s0 + 1, rA1, rA3, aF1, bF1, aF0, bF0);
    slot(s0 + 2, rA2, rA0, aF0, bF0, aF1, bF1);
    slot(s0 + 3, rA3, rA1, aF1, bF1, aF0, bF0);
  }

  // ---- tail slots 28..31 (drain) ----
  // s = 28 (cur F0): no more A loads; last B stage.
  stageB(31);
  __builtin_amdgcn_sched_barrier(0);
  fragRead(29, aF1, bF1);
  mfma16(aF0, bF0);
  waitvm<4>();                         // keep only B(31); A(30),B(30) retired
  writeA(30, rA2);
  asm volatile("s_waitcnt lgkmcnt(0)" ::: "memory");
  __builtin_amdgcn_s_barrier();
  __builtin_amdgcn_sched_barrier(0);
  // s = 29
  fragRead(30, aF0, bF0);
  mfma16(aF1, bF1);
  waitvm<0>();                         // B(31) landed
  writeA(31, rA3);
  asm volatile("s_waitcnt lgkmcnt(0)" ::: "memory");
  __builtin_amdgcn_s_barrier();
  __builtin_amdgcn_sched_barrier(0);
  // s = 30
  fragRead(31, aF1, bF1);
  mfma16(aF0, bF0);
  asm volatile("s_waitcnt lgkmcnt(0)" ::: "memory");
  __builtin_amdgcn_sched_barrier(0);
  // s = 31
  mfma16(aF1, bF1);

  // ---- epilogue: f32 + bias. C/D: col = lane&15, row = (lane>>4)*4+reg ----
  const int col0 = wv * 64;
  float bv[4];
  #pragma unroll
  for (int n = 0; n < 4; ++n) bv[n] = bias[col0 + n * 16 + lr];
  #pragma unroll
  for (int m = 0; m < 4; ++m) {
    #pragma unroll
    for (int i = 0; i < 4; ++i) {
      int r = q0 + m * 16 + (hi << 2) + i;
      #pragma unroll
      for (int n = 0; n < 4; ++n)
        ob[(size_t)r * P_ + col0 + n * 16 + lr] = acc[m][n][i] + bv[n];
    }
  }
}

// ---------------------------------------------------------------------------
// VW GEMM (frozen — identical to round 7): C[MxN] = A[MxK]*B[NxK]^T, f16.
// ---------------------------------------------------------------------------
template<int KK, int BM, int BN, int NW, int WNS>
__global__ __launch_bounds__(NW * 64, 2) void gemm_nt_small(
    const u16* __restrict__ A, const u16* __restrict__ Bm,
    u16* __restrict__ C, long sAb, long sBb, long sCb, int LDC) {
  constexpr int T   = NW * 64;
  constexpr int WMS = NW / WNS;
  constexpr int MF  = BM / (WMS * 16);
  constexpr int NF  = BN / (WNS * 16);
  constexpr int LA  = BM * 8 / T;
  constexpr int LB  = BN * 8 / T;
  constexpr int SZ  = (BM + BN) * 128;
  constexpr int NT  = KK / 64;

  extern __shared__ __align__(16) char smem[];
  const int tid  = threadIdx.x;
  const int lane = tid & 63;
  const int w    = tid >> 6;
  const int wm   = w / WNS;
  const int wn   = w % WNS;
  const int lr   = lane & 15;
  const int hi   = lane >> 4;

  const int bz = blockIdx.z;
  const int I0 = blockIdx.y * BM;
  const int J0 = blockIdx.x * BN;
  const u16* Ab = A  + (long)bz * sAb;
  const u16* Bb = Bm + (long)bz * sBb;

  auto stage = [&](int buf, int k0) {
    char* sA = smem + buf * SZ;
    char* sB = sA + BM * 128;
    #pragma unroll
    for (int i = 0; i < LA; ++i) {
      int cid = i * T + tid;
      int row = cid >> 3;
      int c   = (cid & 7) ^ (row & 7);
      gld_lds16(Ab + (size_t)(I0 + row) * KK + k0 + c * 8, sA + cid * 16);
    }
    #pragma unroll
    for (int i = 0; i < LB; ++i) {
      int cid = i * T + tid;
      int row = cid >> 3;
      int c   = (cid & 7) ^ (row & 7);
      gld_lds16(Bb + (size_t)(J0 + row) * KK + k0 + c * 8, sB + cid * 16);
    }
  };

  f32x4 acc[MF][NF] = {};
  stage(0, 0);
  for (int t = 0; t < NT; ++t) {
    const char* lA = smem + (t & 1) * SZ;
    const char* lB = lA + BM * 128;
    if (t + 1 < NT) {
      stage((t + 1) & 1, (t + 1) * 64);
      asm volatile("s_waitcnt vmcnt(%0)" :: "i"(LA + LB) : "memory");
    } else {
      asm volatile("s_waitcnt vmcnt(0)" ::: "memory");
    }
    __builtin_amdgcn_s_barrier();
    __builtin_amdgcn_sched_barrier(0);
    #pragma unroll
    for (int kk = 0; kk < 2; ++kk) {
      f16x8 af[MF], bfv[NF];
      #pragma unroll
      for (int m = 0; m < MF; ++m) {
        int row = wm * (MF * 16) + m * 16 + lr;
        int cp  = (kk * 4 + hi) ^ (row & 7);
        af[m] = *(const f16x8*)(lA + ((row * 8 + cp) << 4));
      }
      #pragma unroll
      for (int n = 0; n < NF; ++n) {
        int row = wn * (NF * 16) + n * 16 + lr;
        int cp  = (kk * 4 + hi) ^ (row & 7);
        bfv[n] = *(const f16x8*)(lB + ((row * 8 + cp) << 4));
      }
      __builtin_amdgcn_s_setprio(1);
      #pragma unroll
      for (int m = 0; m < MF; ++m)
        #pragma unroll
        for (int n = 0; n < NF; ++n)
          acc[m][n] = __builtin_amdgcn_mfma_f32_16x16x32_f16(af[m], bfv[n], acc[m][n], 0, 0, 0);
      __builtin_amdgcn_s_setprio(0);
    }
    __builtin_amdgcn_sched_barrier(0);
    __builtin_amdgcn_s_barrier();
  }

  const int row0 = I0 + wm * (MF * 16);
  const int col0 = J0 + wn * (NF * 16);
  #pragma unroll
  for (int m = 0; m < MF; ++m)
    #pragma unroll
    for (int i = 0; i < 4; ++i) {
      int r = row0 + m * 16 + (hi << 2) + i;
      #pragma unroll
      for (int n = 0; n < NF; ++n)
        C[(long)bz * sCb + (size_t)r * LDC + col0 + n * 16 + lr] = f2h(acc[m][n][i]);
    }
}

// ---------------------------------------------------------------------------
extern "C" void kernel_launch(void* const* d_in, const int* in_sizes, int n_in,
                              void* d_out, int out_size, void* d_ws, size_t ws_size,
                              hipStream_t stream) {
  const float* data = (const float*)d_in[0];   // [16][1024][512]
  const float* W    = (const float*)d_in[1];   // [256][512]
  const float* bias = (const float*)d_in[2];   // [256]
  float* out = (float*)d_out;                  // [16][2048][256]
  char*  ws  = (char*)d_ws;

  const size_t MB = 1024 * 1024;
  u16*    dataH   = (u16*)(ws);                // 16 MB  [B][S][D] f16
  u16*    Wh      = (u16*)(ws + 16 * MB);      // 256 KB [P][D] f16
  u16*    scoresH = (u16*)(ws + 17 * MB);      // 32 MB  [B][S][S] f16
  u16*    VWT     = (u16*)(ws + 49 * MB);      // 8 MB   [B][P][S] f16
  float2* rowstat = (float2*)(ws + 57 * MB);   // 128 KB [B][S] (m, 1/l)

  const float scale = 0.04419417382415922f;    // 1/sqrt(512)

  constexpr int SMEM_QK = 4 * 32768;             // 128 KB
  constexpr int SMEM_PV = 4 * 4096 + 4 * 16384;  // 80 KB
  constexpr int SMEM_VW = 2 * (64 + 128) * 128;  // 48 KB

  (void)hipFuncSetAttribute((const void*)&qk_pipe,
                      hipFuncAttributeMaxDynamicSharedMemorySize, SMEM_QK);
  (void)hipFuncSetAttribute((const void*)&pv_ring,
                      hipFuncAttributeMaxDynamicSharedMemorySize, SMEM_PV);
  (void)hipFuncSetAttribute((const void*)&gemm_nt_small<512, 64, 128, 4, 2>,
                      hipFuncAttributeMaxDynamicSharedMemorySize, SMEM_VW);

  convert_f16_kernel<<<2048, 256, 0, stream>>>(data, dataH, (long)B_ * S_ * D_ / 4);
  convert_f16_kernel<<<64, 256, 0, stream>>>(W, Wh, (long)P_ * D_ / 4);

  // VWT[b] = Wh (256x512) @ dataH[b]^T -> [256][1024] f16
  gemm_nt_small<512, 64, 128, 4, 2><<<dim3(8, 4, 16), 256, SMEM_VW, stream>>>(
      Wh, dataH, VWT, 0L, (long)S_ * D_, (long)P_ * S_, S_);

  // scoresH[b] = scale * dataH[b] @ dataH[b]^T -> [1024][1024] f16
  qk_pipe<<<dim3(4, 4, 16), 512, SMEM_QK, stream>>>(dataH, scoresH, scale);

  // rowstat = per-row (max, 1/sumexp)
  stats_kernel<<<4096, 256, 0, stream>>>(scoresH, rowstat);

  // out[b][:S] = softmax(scoresH[b]) @ VWT[b]^T + bias; tail rows zeroed
  pv_ring<<<dim3(1, 32, 16), 256, SMEM_PV, stream>>>(
      scoresH, VWT, rowstat, out, bias);
}